// Round 10
// baseline (166.106 us; speedup 1.0000x reference)
//
#include <hip/hip_runtime.h>

#define DIM     1024
#define BATCH   512
#define OUTD    5377
#define NHEADS  10
#define NLAYERS 5
#define LDK     72   // padded bf16 leading dim for MLP tiles

typedef __attribute__((ext_vector_type(4))) float f32x4;
typedef __attribute__((ext_vector_type(8))) short bf16x8;

__device__ __forceinline__ unsigned short f2bf(float f) {
    unsigned u = __builtin_bit_cast(unsigned, f);
    u = (u + 0x7FFFu + ((u >> 16) & 1u)) >> 16;
    return (unsigned short)u;
}
__device__ __forceinline__ float bf2f(unsigned short h) {
    unsigned u = ((unsigned)h) << 16;
    return __builtin_bit_cast(float, u);
}
__device__ __forceinline__ unsigned pk2(float a, float b) {
    return (unsigned)f2bf(a) | ((unsigned)f2bf(b) << 16);
}

// ---------------- grouping: bucket batches by rule_len ----------------
__global__ void group_kernel(const int* __restrict__ rule_len,
                             int* __restrict__ bidx,
                             int* __restrict__ gstart,
                             int* __restrict__ gcount) {
    __shared__ int s_count[NHEADS];
    __shared__ int s_fill[NHEADS];
    int t = threadIdx.x;
    if (t < NHEADS) s_count[t] = 0;
    __syncthreads();
    int h = rule_len[t];
    atomicAdd(&s_count[h], 1);
    __syncthreads();
    if (t == 0) {
        int acc = 0;
        for (int i = 0; i < NHEADS; ++i) {
            gstart[i] = acc;
            gcount[i] = s_count[i];
            s_fill[i] = acc;
            acc += s_count[i];
        }
    }
    __syncthreads();
    int pos = atomicAdd(&s_fill[h], 1);
    bidx[pos] = t;
}

// ---------------- latent f32 -> bf16 ----------------
__global__ void convert_latent(const float* __restrict__ in,
                               unsigned short* __restrict__ out) {
    int i = blockIdx.x * blockDim.x + threadIdx.x;   // one float4 per thread
    float4 v = ((const float4*)in)[i];
    ushort4 o;
    o.x = f2bf(v.x); o.y = f2bf(v.y); o.z = f2bf(v.z); o.w = f2bf(v.w);
    ((ushort4*)out)[i] = o;
}

// ---------------- MLP layer: C = A @ W^T + bias  (MFMA, W hi/lo, pipelined) --
// (R3-proven version: inline hi/lo convert, single barrier per K-step)
__global__ __launch_bounds__(256) void mlp_mfma(
    const unsigned short* __restrict__ A,
    const float* __restrict__ W,
    const float* __restrict__ bias,
    unsigned short* __restrict__ C)
{
    __shared__ __align__(16) unsigned short As[2][32][LDK];
    __shared__ __align__(16) unsigned short Whi[2][32][LDK];
    __shared__ __align__(16) unsigned short Wlo[2][32][LDK];

    const int tid = threadIdx.x;
    const int n0 = blockIdx.x * 32;
    const int m0 = blockIdx.y * 32;
    const int lane = tid & 63;
    const int wid = tid >> 6;
    const int wm = (wid >> 1) * 16;
    const int wn = (wid & 1) * 16;

    f32x4 acc = {0.f, 0.f, 0.f, 0.f};

    const int ar = tid >> 3;          // 0..31
    const int ac = (tid & 7) * 8;     // 0..56 bf16 units
    const int wr = tid >> 4;          // 0..15
    const int wc = (tid & 15) * 4;    // 0..60 f32 units

    const unsigned short* Ap = A + (size_t)(m0 + ar) * DIM + ac;
    const float* Wp0 = W + (size_t)(n0 + wr) * DIM + wc;
    const float* Wp1 = W + (size_t)(n0 + wr + 16) * DIM + wc;

    uint4  ra  = *(const uint4*)(Ap);
    float4 rw0 = *(const float4*)(Wp0);
    float4 rw1 = *(const float4*)(Wp1);

    for (int t = 0; t < DIM / 64; ++t) {
        const int cur = t & 1;
        *(uint4*)&As[cur][ar][ac] = ra;
        {
            ushort4 hi, lo;
            hi.x = f2bf(rw0.x); lo.x = f2bf(rw0.x - bf2f(hi.x));
            hi.y = f2bf(rw0.y); lo.y = f2bf(rw0.y - bf2f(hi.y));
            hi.z = f2bf(rw0.z); lo.z = f2bf(rw0.z - bf2f(hi.z));
            hi.w = f2bf(rw0.w); lo.w = f2bf(rw0.w - bf2f(hi.w));
            *(ushort4*)&Whi[cur][wr][wc] = hi;
            *(ushort4*)&Wlo[cur][wr][wc] = lo;
            hi.x = f2bf(rw1.x); lo.x = f2bf(rw1.x - bf2f(hi.x));
            hi.y = f2bf(rw1.y); lo.y = f2bf(rw1.y - bf2f(hi.y));
            hi.z = f2bf(rw1.z); lo.z = f2bf(rw1.z - bf2f(hi.z));
            hi.w = f2bf(rw1.w); lo.w = f2bf(rw1.w - bf2f(hi.w));
            *(ushort4*)&Whi[cur][wr + 16][wc] = hi;
            *(ushort4*)&Wlo[cur][wr + 16][wc] = lo;
        }
        __syncthreads();
        if (t < DIM / 64 - 1) {
            const int k0 = (t + 1) * 64;
            ra  = *(const uint4*)(Ap + k0);
            rw0 = *(const float4*)(Wp0 + k0);
            rw1 = *(const float4*)(Wp1 + k0);
        }
        #pragma unroll
        for (int kk = 0; kk < 2; ++kk) {
            const int ko = kk * 32 + (lane >> 4) * 8;
            bf16x8 a  = *(const bf16x8*)&As[cur][wm + (lane & 15)][ko];
            bf16x8 bh = *(const bf16x8*)&Whi[cur][wn + (lane & 15)][ko];
            bf16x8 bl = *(const bf16x8*)&Wlo[cur][wn + (lane & 15)][ko];
            acc = __builtin_amdgcn_mfma_f32_16x16x32_bf16(a, bh, acc, 0, 0, 0);
            acc = __builtin_amdgcn_mfma_f32_16x16x32_bf16(a, bl, acc, 0, 0, 0);
        }
    }

    const int cn = n0 + wn + (lane & 15);
    const float bn = bias[cn];
    const int rbase = m0 + wm + (lane >> 4) * 4;
    #pragma unroll
    for (int j = 0; j < 4; ++j) {
        C[(size_t)(rbase + j) * DIM + cn] = f2bf(acc[j] + bn);
    }
}

// ------- head "row-sequential": whole-K W tile staged once, 1 barrier --------
// Block: 256 threads, 4 waves. Tile: 64 m x 32 n x full K=1024.
// Stage: 16 passes; pass p reads rows 2p (threads 0-127) and 2p+1 (128-255)
// as whole contiguous 4 KB bursts -> bf16-pack -> XOR-swizzled LDS granules.
// Global read order is row-sequential (page-local), ~2 streams/block.
// Compute: barrier-free 16-step MFMA loop; per wave 32m x 16n output.
__global__ __launch_bounds__(256) void head_rs(
    const unsigned short* __restrict__ H,   // BATCH x DIM bf16
    const float* __restrict__ Wh,           // NHEADS x OUTD x DIM f32
    const float* __restrict__ bh,           // NHEADS x OUTD f32
    const int* __restrict__ bidx,
    const int* __restrict__ gstart,
    const int* __restrict__ gcount,
    float* __restrict__ out)                // BATCH x OUTD f32
{
    const int head = blockIdx.z;
    const int cnt  = gcount[head];
    const int m0   = blockIdx.y * 64;
    if (m0 >= cnt) return;
    const int start = gstart[head];
    const int n0 = blockIdx.x * 32;

    __shared__ __align__(16) unsigned short Wt[32][1024];   // 64 KB
    __shared__ int s_b[64];

    const int tid = threadIdx.x;
    if (tid < 64) {
        int mi = m0 + tid;
        s_b[tid] = bidx[start + ((mi < cnt) ? mi : (cnt - 1))];
    }

    // ---- stage W: row-sequential contiguous reads ----
    const float* WhL = Wh + (size_t)head * OUTD * DIM;
    const int half = tid >> 7;          // 0/1: which row of the pair
    const int lid  = tid & 127;         // 32-B chunk index within the row
    char* lds = (char*)&Wt[0][0];
    #pragma unroll
    for (int p = 0; p < 16; ++p) {
        const int r = 2 * p + half;
        int grow = n0 + r; if (grow > OUTD - 1) grow = OUTD - 1;
        const float* src = WhL + (size_t)grow * DIM + lid * 8;
        float4 v0 = *(const float4*)(src);
        float4 v1 = *(const float4*)(src + 4);
        uint4 wk;
        wk.x = pk2(v0.x, v0.y); wk.y = pk2(v0.z, v0.w);
        wk.z = pk2(v1.x, v1.y); wk.w = pk2(v1.z, v1.w);
        // granule = lid (16 B), swizzled by row for conflict-free frag reads
        *(uint4*)(lds + r * 2048 + ((lid ^ (r & 7)) << 4)) = wk;
    }
    __syncthreads();   // the only barrier

    // ---- compute ----
    const int lane = tid & 63;
    const int wv   = tid >> 6;
    const int col  = lane & 15;
    const int hk   = lane >> 4;
    const int wm   = (wv >> 1) * 32;    // 0 or 32 (m-slice)
    const int wn   = (wv & 1) * 16;     // 0 or 16 (n-slice)

    const char* Ab[2];
    #pragma unroll
    for (int mf = 0; mf < 2; ++mf) {
        Ab[mf] = (const char*)(H + (size_t)s_b[wm + mf * 16 + col] * DIM) + hk * 16;
    }

    const int nr = wn + col;            // LDS W row this lane consumes
    const int rowbase = nr * 2048;
    const int rsw = (nr & 7) << 4;

    f32x4 acc[2] = {};
    #pragma unroll
    for (int step = 0; step < 16; ++step) {
        bf16x8 b0 = *(const bf16x8*)(lds + rowbase + ((((step * 8 + 0 + hk)) << 4) ^ rsw));
        bf16x8 b1 = *(const bf16x8*)(lds + rowbase + ((((step * 8 + 4 + hk)) << 4) ^ rsw));
        uint4 a00 = *(const uint4*)(Ab[0] + step * 128);
        uint4 a01 = *(const uint4*)(Ab[0] + step * 128 + 64);
        uint4 a10 = *(const uint4*)(Ab[1] + step * 128);
        uint4 a11 = *(const uint4*)(Ab[1] + step * 128 + 64);
        acc[0] = __builtin_amdgcn_mfma_f32_16x16x32_bf16(
            __builtin_bit_cast(bf16x8, a00), b0, acc[0], 0, 0, 0);
        acc[0] = __builtin_amdgcn_mfma_f32_16x16x32_bf16(
            __builtin_bit_cast(bf16x8, a01), b1, acc[0], 0, 0, 0);
        acc[1] = __builtin_amdgcn_mfma_f32_16x16x32_bf16(
            __builtin_bit_cast(bf16x8, a10), b0, acc[1], 0, 0, 0);
        acc[1] = __builtin_amdgcn_mfma_f32_16x16x32_bf16(
            __builtin_bit_cast(bf16x8, a11), b1, acc[1], 0, 0, 0);
    }

    const int n = n0 + nr;
    if (n < OUTD) {
        const float bn = bh[(size_t)head * OUTD + n];
        #pragma unroll
        for (int mf = 0; mf < 2; ++mf) {
            #pragma unroll
            for (int j = 0; j < 4; ++j) {
                int lm = wm + mf * 16 + hk * 4 + j;
                if (m0 + lm < cnt) {
                    out[(size_t)s_b[lm] * OUTD + n] = acc[mf][j] + bn;
                }
            }
        }
    }
}

extern "C" void kernel_launch(void* const* d_in, const int* in_sizes, int n_in,
                              void* d_out, int out_size, void* d_ws, size_t ws_size,
                              hipStream_t stream) {
    const float* latent   = (const float*)d_in[0];
    const float* W_mlp    = (const float*)d_in[1];
    const float* b_mlp    = (const float*)d_in[2];
    const float* W_heads  = (const float*)d_in[3];
    const float* b_heads  = (const float*)d_in[4];
    const int*   rule_len = (const int*)d_in[5];
    float* out = (float*)d_out;

    unsigned short* h0 = (unsigned short*)d_ws;
    unsigned short* h1 = h0 + (size_t)BATCH * DIM;
    int* bidx   = (int*)(h1 + (size_t)BATCH * DIM);
    int* gstart = bidx + BATCH;
    int* gcount = gstart + 16;

    group_kernel<<<1, BATCH, 0, stream>>>(rule_len, bidx, gstart, gcount);
    convert_latent<<<(BATCH * DIM / 4) / 256, 256, 0, stream>>>(latent, h0);

    dim3 mgrid(DIM / 32, BATCH / 32);
    const unsigned short* src = h0;
    unsigned short* dst = h1;
    for (int l = 0; l < NLAYERS; ++l) {
        mlp_mfma<<<mgrid, 256, 0, stream>>>(src,
                                            W_mlp + (size_t)l * DIM * DIM,
                                            b_mlp + (size_t)l * DIM,
                                            dst);
        unsigned short* t = (unsigned short*)src;
        src = dst;
        dst = t;
    }

    dim3 hgrid((OUTD + 31) / 32, 2, NHEADS);
    head_rs<<<hgrid, 256, 0, stream>>>(src, W_heads, b_heads,
                                       bidx, gstart, gcount, out);
}